// Round 18
// baseline (173.356 us; speedup 1.0000x reference)
//
#include <hip/hip_runtime.h>
#include <hip/hip_bf16.h>
#include <cstdint>

// ---------------------------------------------------------------------------
// GNN encoder: 3 x { agg = segment_sum(z[src], dst); h = z + agg;
//                    t = relu(h@w1+b1); z = relu(t@w2+b2) }
// CSR build per call. z bf16 between layers.
// agg: 128B-slice gather + pipelined srcs prefetch (r17).
// GEMMs r18: DE-FUSED. 6 simple GEMMs, 64x64 tile, 628 blocks (2.45/CU,
// smooth coverage vs fused 157-block grid quantization). Stage A-panel +
// W-panel once (64KB LDS @K=256 -> 2 blocks/CU), ONE barrier, pure
// ds_read+MFMA k-loop. k-order per output linear = fused order -> bitwise-same.
// scan: wave-shuffle. wconv: coalesced LDS transpose.
// ---------------------------------------------------------------------------

#define NNODES 10000
#define NEDGES 320000
#define DIN 128
#define DH 256

typedef __bf16 bf16x8 __attribute__((ext_vector_type(8)));
typedef unsigned short ushort8v __attribute__((ext_vector_type(8)));
typedef unsigned short ushort4v __attribute__((ext_vector_type(4)));
typedef float f32x4 __attribute__((ext_vector_type(4)));

__device__ __forceinline__ unsigned short f2bf(float f) {
    unsigned int u = __float_as_uint(f);
    unsigned int r = u + 0x7fffu + ((u >> 16) & 1u);   // round-to-nearest-even
    return (unsigned short)(r >> 16);
}
__device__ __forceinline__ float bf2f(unsigned short u) {
    return __uint_as_float(((unsigned int)u) << 16);
}

// --- fused prep: [0,40) zero cnt | [40] detect i32/i64 | [41,1291) xconv |
// rest: wconv via coalesced 32x32 LDS-transpose tiles
struct PrepArgs {
    const float* wsrc[6];
    unsigned short* wdst[6];
    int wkbits[6];
    const int* eb;
    int* flag;
    int* cnt;
    const float* x;
    unsigned short* xb;
};
#define PREP_ZERO_B 40
#define PREP_XCONV_B 1250
#define PREP_WCONV_B 352   // 32 tiles (m0: 4x8) + 5*64 tiles (8x8)
#define PREP_GRID (PREP_ZERO_B + 1 + PREP_XCONV_B + PREP_WCONV_B)

__global__ void prep_kernel(PrepArgs a) {
    __shared__ float tile[32][33];
    __shared__ int any;
    int bid = blockIdx.x;
    int tid = threadIdx.x;
    if (bid < PREP_ZERO_B) {
        int i = bid * 256 + tid;
        if (i < NNODES) a.cnt[i] = 0;
    } else if (bid == PREP_ZERO_B) {
        if (tid == 0) any = 0;
        __syncthreads();
        for (int i = tid; i < 1024; i += 256)
            if (a.eb[2 * i + 1] != 0) any = 1;
        __syncthreads();
        if (tid == 0) a.flag[0] = any;   // 1 => int32 storage, 0 => int64
    } else if (bid < PREP_ZERO_B + 1 + PREP_XCONV_B) {
        int i = (bid - PREP_ZERO_B - 1) * 256 + tid;
        if (i < NNODES * DIN / 4) {
            float4 v = reinterpret_cast<const float4*>(a.x)[i];
            ushort4v o = {f2bf(v.x), f2bf(v.y), f2bf(v.z), f2bf(v.w)};
            reinterpret_cast<ushort4v*>(a.xb)[i] = o;
        }
    } else {
        // transpose+convert one 32x32 tile: src fp32 [K][256] -> dst bf16 [256][K]
        int wb = bid - (PREP_ZERO_B + 1 + PREP_XCONV_B);
        int m, t32;
        if (wb < 32) { m = 0; t32 = wb; }
        else { m = 1 + (wb - 32) / 64; t32 = (wb - 32) % 64; }
        int kb = a.wkbits[m];
        int K = 1 << kb;
        int tc = t32 & 7, tr = t32 >> 3;          // tr < K/32
        int r = tid >> 3, c4 = (tid & 7) * 4;     // load coalesced rows
        float4 v = *reinterpret_cast<const float4*>(
            &a.wsrc[m][(size_t)(tr * 32 + r) * 256 + tc * 32 + c4]);
        tile[r][c4 + 0] = v.x; tile[r][c4 + 1] = v.y;
        tile[r][c4 + 2] = v.z; tile[r][c4 + 3] = v.w;
        __syncthreads();
        int cc = tid >> 3, k4 = (tid & 7) * 4;    // write coalesced dst rows
        ushort4v o = {f2bf(tile[k4 + 0][cc]), f2bf(tile[k4 + 1][cc]),
                      f2bf(tile[k4 + 2][cc]), f2bf(tile[k4 + 3][cc])};
        *reinterpret_cast<ushort4v*>(
            &a.wdst[m][(size_t)(tc * 32 + cc) * K + tr * 32 + k4]) = o;
    }
}

__device__ __forceinline__ int eload(const int* __restrict__ eb, int is32, long logical_idx) {
    return is32 ? eb[logical_idx] : eb[2 * logical_idx]; // little-endian low word
}

__global__ void hist_kernel(const int* __restrict__ eb, const int* __restrict__ flag,
                            int* __restrict__ cnt, int E) {
    int i = blockIdx.x * blockDim.x + threadIdx.x;
    if (i >= E) return;
    int is32 = flag[0];
    int d = eload(eb, is32, (long)E + i);
    atomicAdd(&cnt[d], 1);
}

// single-block exclusive scan over N counts -> offs[N+1], cursor copy.
// Wave-shuffle scan: per-wave __shfl_up inclusive scan, 16 wave sums scanned
// by wave 0, 2 barriers total.
__global__ __launch_bounds__(1024) void scan_kernel(const int* __restrict__ cnt,
                                                    int* __restrict__ offs,
                                                    int* __restrict__ cursor, int n) {
    __shared__ int wsums[16];
    int tid = threadIdx.x, lane = tid & 63, wid = tid >> 6;
    int per = (n + 1023) / 1024;          // 10 for n=10000
    int beg = tid * per;
    int local[16];
    int s = 0;
    for (int i = 0; i < per; ++i) {
        int idx = beg + i;
        int v = (idx < n) ? cnt[idx] : 0;
        local[i] = s;
        s += v;
    }
    int inc = s;                           // inclusive scan within wave
    for (int d = 1; d < 64; d <<= 1) {
        int y = __shfl_up(inc, d, 64);
        if (lane >= d) inc += y;
    }
    if (lane == 63) wsums[wid] = inc;
    __syncthreads();
    if (tid < 16) {
        int v = wsums[tid];
        for (int d = 1; d < 16; d <<= 1) {
            int y = __shfl_up(v, d, 64);
            if (tid >= d) v += y;
        }
        wsums[tid] = v;                    // inclusive wave-sum prefix
    }
    __syncthreads();
    int wbase = (wid > 0) ? wsums[wid - 1] : 0;
    int base = wbase + inc - s;            // exclusive prefix of this chunk
    for (int i = 0; i < per; ++i) {
        int idx = beg + i;
        if (idx < n) {
            int v = base + local[i];
            offs[idx] = v;
            cursor[idx] = v;
        }
    }
    if (tid == 1023) offs[n] = wbase + inc;
}

__global__ void scatter_kernel(const int* __restrict__ eb, const int* __restrict__ flag,
                               int* __restrict__ cursor, int* __restrict__ srcs, int E) {
    int i = blockIdx.x * blockDim.x + threadIdx.x;
    if (i >= E) return;
    int is32 = flag[0];
    int s = eload(eb, is32, (long)i);
    int d = eload(eb, is32, (long)E + i);
    int pos = atomicAdd(&cursor[d], 1);
    srcs[pos] = s;
}

// --- sliced bf16 aggregation: h[i] = z[i] + sum_{e in CSR[i]} z[src_e].
// 128B slices: LPN=8 lanes x ushort8 (16B) = one 128B cache line per
// node-slice. slice = bid & (NSLICE-1) -> round-robin XCD binding; per-XCD
// working set N*128B = 1.28 MB (L2-resident). 4 gather chains + software-
// pipelined srcs prefetch.
template <int D>
__global__ __launch_bounds__(256) void agg_add_sliced_kernel(const unsigned short* __restrict__ z,
                                                             const int* __restrict__ srcs,
                                                             const int* __restrict__ offs,
                                                             unsigned short* __restrict__ h, int n) {
    constexpr int NSLICE = (D * 2) / 128;  // 4 for D=256, 2 for D=128
    constexpr int LPN = 8;                 // 8 lanes x 16B = 128B per node-slice
    constexpr int NPB = 256 / LPN;         // 32 nodes per block
    int bid = blockIdx.x;
    int slice = bid & (NSLICE - 1);
    int ng = bid / NSLICE;
    int t = threadIdx.x;
    int node = ng * NPB + t / LPN;
    if (node >= n) return;
    int li = t % LPN;
    int col8 = slice * LPN + li;          // ushort8 column index within row
    const ushort8v* zb = reinterpret_cast<const ushort8v*>(z);
    const int ld8 = D / 8;
    int beg = offs[node], end = offs[node + 1];

    float a0[8] = {}, a1[8] = {}, a2[8] = {}, a3[8] = {};
    int e = beg;
    if (e + 4 <= end) {
        int s0 = srcs[e], s1 = srcs[e + 1], s2 = srcs[e + 2], s3 = srcs[e + 3];
        while (true) {
            int n0 = 0, n1 = 0, n2 = 0, n3 = 0;
            bool more = (e + 8 <= end);
            if (more) {
                n0 = srcs[e + 4]; n1 = srcs[e + 5];
                n2 = srcs[e + 6]; n3 = srcs[e + 7];
            }
            ushort8v v0 = zb[(size_t)s0 * ld8 + col8];
            ushort8v v1 = zb[(size_t)s1 * ld8 + col8];
            ushort8v v2 = zb[(size_t)s2 * ld8 + col8];
            ushort8v v3 = zb[(size_t)s3 * ld8 + col8];
#pragma unroll
            for (int j = 0; j < 8; ++j) {
                a0[j] += bf2f(v0[j]);
                a1[j] += bf2f(v1[j]);
                a2[j] += bf2f(v2[j]);
                a3[j] += bf2f(v3[j]);
            }
            e += 4;
            if (!more) break;
            s0 = n0; s1 = n1; s2 = n2; s3 = n3;
        }
    }
    for (; e < end; ++e) {
        ushort8v v = zb[(size_t)srcs[e] * ld8 + col8];
#pragma unroll
        for (int j = 0; j < 8; ++j) a0[j] += bf2f(v[j]);
    }
    ushort8v zr = zb[(size_t)node * ld8 + col8];   // residual z term
    ushort8v o;
#pragma unroll
    for (int j = 0; j < 8; ++j) {
        float v = a0[j] + a1[j] + a2[j] + a3[j] + bf2f(zr[j]);
        o[j] = f2bf(v);
    }
    reinterpret_cast<ushort8v*>(h)[(size_t)node * ld8 + col8] = o;
}

// --- GEMM r18: C = relu(A @ W + bias). A: MxK bf16, Wt: 256xK bf16 (transposed),
// C: Mx256 (bf16 or fp32). 64x64 tile, grid (M/64, 4), 256 thr / 4 waves,
// wave tile 32x32 (wr=wave>>1, wc=wave&1), acc[2][2].
// Stage A-panel + W-panel once -> ONE barrier -> pure ds_read+MFMA k-loop.
// LDS = 2 * K*64*2B (64KB @K=256 -> 2 blocks/CU; 32KB @K=128).
// k-chunk order linear 0..NK-1 per output = previous fused order -> bitwise-same.
// MFMA layouts (m89-verified): A-frag row=lane&15, k=(lane>>4)*8+j;
// C/D col=lane&15, row=(lane>>4)*4+j.
template <int K, int OUT_BF16>
__global__ __launch_bounds__(256) void gemm_kernel(const unsigned short* __restrict__ A,
                                                   const unsigned short* __restrict__ Wt,
                                                   const float* __restrict__ bias,
                                                   void* __restrict__ C, int M) {
    constexpr int NK = K / 32;                   // k-chunks (4 or 8)
    __shared__ unsigned short As[NK][4][64][8];  // 16/32 KB  A panel (fragment order)
    __shared__ unsigned short Bs[NK][4][64][8];  // 16/32 KB  W panel (64 cols)
    int tid = threadIdx.x;
    int wave = tid >> 6, lane = tid & 63;
    int wr = wave >> 1, wc = wave & 1;           // 2x2 wave grid
    int m0 = blockIdx.x * 64;
    int n0 = blockIdx.y * 64;
    int fr = lane & 15;        // fragment row/col
    int kc = lane >> 4;        // fragment k-chunk (== rg for C/D rows)

    f32x4 acc[2][2];
#pragma unroll
    for (int i = 0; i < 2; ++i)
#pragma unroll
        for (int j = 0; j < 2; ++j) acc[i][j] = (f32x4){0.f, 0.f, 0.f, 0.f};

    // ---- stage A panel (64 x K) + W panel (64 cols x K), one pass
    {
        int row = tid >> 2, c0 = tid & 3;        // 4 threads per row
        int gr = m0 + row;
#pragma unroll
        for (int i = 0; i < K / 32; ++i) {       // chunks per thread
            int chunk = c0 + i * 4;
            ushort8v av = {0, 0, 0, 0, 0, 0, 0, 0};
            if (gr < M) av = *reinterpret_cast<const ushort8v*>(&A[(size_t)gr * K + chunk * 8]);
            *reinterpret_cast<ushort8v*>(&As[chunk >> 2][chunk & 3][row][0]) = av;
            ushort8v bv = *reinterpret_cast<const ushort8v*>(&Wt[(size_t)(n0 + row) * K + chunk * 8]);
            *reinterpret_cast<ushort8v*>(&Bs[chunk >> 2][chunk & 3][row][0]) = bv;
        }
    }
    __syncthreads();

    // ---- k-loop: pure ds_read + MFMA, no barriers
#pragma unroll
    for (int kk = 0; kk < NK; ++kk) {
        bf16x8 af[2], bf[2];
#pragma unroll
        for (int i = 0; i < 2; ++i)
            af[i] = __builtin_bit_cast(bf16x8,
                *reinterpret_cast<const ushort8v*>(&As[kk][kc][wr * 32 + i * 16 + fr][0]));
#pragma unroll
        for (int j = 0; j < 2; ++j)
            bf[j] = __builtin_bit_cast(bf16x8,
                *reinterpret_cast<const ushort8v*>(&Bs[kk][kc][wc * 32 + j * 16 + fr][0]));
#pragma unroll
        for (int i = 0; i < 2; ++i)
#pragma unroll
            for (int j = 0; j < 2; ++j)
                acc[i][j] = __builtin_amdgcn_mfma_f32_16x16x32_bf16(af[i], bf[j], acc[i][j], 0, 0, 0);
    }

    // ---- epilogue
#pragma unroll
    for (int i = 0; i < 2; ++i)
#pragma unroll
        for (int j = 0; j < 2; ++j) {
            int col = n0 + wc * 32 + j * 16 + fr;
            float bb = bias[col];
#pragma unroll
            for (int jj = 0; jj < 4; ++jj) {
                int row = m0 + wr * 32 + i * 16 + kc * 4 + jj;
                if (row < M) {
                    float v = fmaxf(acc[i][j][jj] + bb, 0.f);
                    if (OUT_BF16)
                        ((unsigned short*)C)[(size_t)row * 256 + col] = f2bf(v);
                    else
                        ((float*)C)[(size_t)row * 256 + col] = v;
                }
            }
        }
}

extern "C" void kernel_launch(void* const* d_in, const int* in_sizes, int n_in,
                              void* d_out, int out_size, void* d_ws, size_t ws_size,
                              hipStream_t stream) {
    const float* x = (const float*)d_in[0];
    const int* eb = (const int*)d_in[1];
    const int E = NEDGES;
    const int N = NNODES;

    const float* w1[3] = {(const float*)d_in[2], (const float*)d_in[6], (const float*)d_in[10]};
    const float* b1[3] = {(const float*)d_in[3], (const float*)d_in[7], (const float*)d_in[11]};
    const float* w2[3] = {(const float*)d_in[4], (const float*)d_in[8], (const float*)d_in[12]};
    const float* b2[3] = {(const float*)d_in[5], (const float*)d_in[9], (const float*)d_in[13]};

    // workspace layout
    char* ws = (char*)d_ws;
    size_t off = 0;
    auto alloc = [&](size_t bytes) {
        void* p = ws + off;
        off += (bytes + 255) & ~(size_t)255;
        return p;
    };
    int* flag   = (int*)alloc(4);
    int* cnt    = (int*)alloc((size_t)N * 4);
    int* offs   = (int*)alloc((size_t)(N + 1) * 4);
    int* cursor = (int*)alloc((size_t)N * 4);
    int* srcs   = (int*)alloc((size_t)E * 4);
    unsigned short* xb   = (unsigned short*)alloc((size_t)N * DIN * 2);
    unsigned short* zbuf = (unsigned short*)alloc((size_t)N * DH * 2);
    unsigned short* hbuf = (unsigned short*)alloc((size_t)N * DH * 2);
    unsigned short* tbuf = (unsigned short*)alloc((size_t)N * DH * 2);
    unsigned short* wt[6];
    wt[0] = (unsigned short*)alloc((size_t)DIN * DH * 2);          // w1_0^T: 256x128
    for (int i = 1; i < 6; ++i) wt[i] = (unsigned short*)alloc((size_t)DH * DH * 2);
    (void)ws_size; (void)n_in; (void)out_size; (void)in_sizes;

    // --- fused prep (zero cnt | detect | x->bf16 | weights ->bf16 transposed)
    PrepArgs pa;
    pa.wsrc[0] = w1[0]; pa.wsrc[1] = w2[0]; pa.wsrc[2] = w1[1];
    pa.wsrc[3] = w2[1]; pa.wsrc[4] = w1[2]; pa.wsrc[5] = w2[2];
    for (int i = 0; i < 6; ++i) pa.wdst[i] = wt[i];
    pa.wkbits[0] = 7;
    for (int i = 1; i < 6; ++i) pa.wkbits[i] = 8;
    pa.eb = eb; pa.flag = flag; pa.cnt = cnt; pa.x = x; pa.xb = xb;
    prep_kernel<<<PREP_GRID, 256, 0, stream>>>(pa);

    // --- CSR build
    hist_kernel<<<(E + 255) / 256, 256, 0, stream>>>(eb, flag, cnt, E);
    scan_kernel<<<1, 1024, 0, stream>>>(cnt, offs, cursor, N);
    scatter_kernel<<<(E + 255) / 256, 256, 0, stream>>>(eb, flag, cursor, srcs, E);

    dim3 gemm_grid((N + 63) / 64, 4);           // 157 x 4 = 628 blocks
    int agg_blocks_256 = ((N + 31) / 32) * 4;   // D=256: 32 nodes/block, 4 slices
    int agg_blocks_128 = ((N + 31) / 32) * 2;   // D=128: 32 nodes/block, 2 slices

    // --- layer 0 (K = 128)
    agg_add_sliced_kernel<128><<<agg_blocks_128, 256, 0, stream>>>(xb, srcs, offs, hbuf, N);
    gemm_kernel<128, 1><<<gemm_grid, 256, 0, stream>>>(hbuf, wt[0], b1[0], tbuf, N);
    gemm_kernel<256, 1><<<gemm_grid, 256, 0, stream>>>(tbuf, wt[1], b2[0], zbuf, N);

    // --- layer 1
    agg_add_sliced_kernel<256><<<agg_blocks_256, 256, 0, stream>>>(zbuf, srcs, offs, hbuf, N);
    gemm_kernel<256, 1><<<gemm_grid, 256, 0, stream>>>(hbuf, wt[2], b1[1], tbuf, N);
    gemm_kernel<256, 1><<<gemm_grid, 256, 0, stream>>>(tbuf, wt[3], b2[1], zbuf, N);

    // --- layer 2 (final output fp32 to d_out)
    agg_add_sliced_kernel<256><<<agg_blocks_256, 256, 0, stream>>>(zbuf, srcs, offs, hbuf, N);
    gemm_kernel<256, 1><<<gemm_grid, 256, 0, stream>>>(hbuf, wt[4], b1[2], tbuf, N);
    gemm_kernel<256, 0><<<gemm_grid, 256, 0, stream>>>(tbuf, wt[5], b2[2], (float*)d_out, N);
}

// Round 19
// 146.479 us; speedup vs baseline: 1.1835x; 1.1835x over previous
//
#include <hip/hip_runtime.h>
#include <hip/hip_bf16.h>
#include <cstdint>

// ---------------------------------------------------------------------------
// GNN encoder: 3 x { agg = segment_sum(z[src], dst); h = z + agg;
//                    t = relu(h@w1+b1); z = relu(t@w2+b2) }
// FINAL config (= r16 best, 146.7us; r18 de-fuse regressed +27us, reverted):
// - CSR build per call (hist + wave-shuffle scan + scatter), no float atomics
// - z bf16 between layers; agg: 128B-slice gather, slice->XCD L2 residency,
//   4 independent chains + pipelined srcs prefetch
// - MLP: both GEMMs fused, 64-row/8-wave blocks, 32x64 wave tiles, 128-k
//   W slices, T14 reg-prefetch staging, t lives in LDS only
// - prep fused (zero|detect|xconv|coalesced wconv transpose)
// ---------------------------------------------------------------------------

#define NNODES 10000
#define NEDGES 320000
#define DIN 128
#define DH 256

typedef __bf16 bf16x8 __attribute__((ext_vector_type(8)));
typedef unsigned short ushort8v __attribute__((ext_vector_type(8)));
typedef unsigned short ushort4v __attribute__((ext_vector_type(4)));
typedef float f32x4 __attribute__((ext_vector_type(4)));

__device__ __forceinline__ unsigned short f2bf(float f) {
    unsigned int u = __float_as_uint(f);
    unsigned int r = u + 0x7fffu + ((u >> 16) & 1u);   // round-to-nearest-even
    return (unsigned short)(r >> 16);
}
__device__ __forceinline__ float bf2f(unsigned short u) {
    return __uint_as_float(((unsigned int)u) << 16);
}

// --- fused prep: [0,40) zero cnt | [40] detect i32/i64 | [41,1291) xconv |
// rest: wconv via coalesced 32x32 LDS-transpose tiles
struct PrepArgs {
    const float* wsrc[6];
    unsigned short* wdst[6];
    int wkbits[6];
    const int* eb;
    int* flag;
    int* cnt;
    const float* x;
    unsigned short* xb;
};
#define PREP_ZERO_B 40
#define PREP_XCONV_B 1250
#define PREP_WCONV_B 352   // 32 tiles (m0: 4x8) + 5*64 tiles (8x8)
#define PREP_GRID (PREP_ZERO_B + 1 + PREP_XCONV_B + PREP_WCONV_B)

__global__ void prep_kernel(PrepArgs a) {
    __shared__ float tile[32][33];
    __shared__ int any;
    int bid = blockIdx.x;
    int tid = threadIdx.x;
    if (bid < PREP_ZERO_B) {
        int i = bid * 256 + tid;
        if (i < NNODES) a.cnt[i] = 0;
    } else if (bid == PREP_ZERO_B) {
        if (tid == 0) any = 0;
        __syncthreads();
        for (int i = tid; i < 1024; i += 256)
            if (a.eb[2 * i + 1] != 0) any = 1;
        __syncthreads();
        if (tid == 0) a.flag[0] = any;   // 1 => int32 storage, 0 => int64
    } else if (bid < PREP_ZERO_B + 1 + PREP_XCONV_B) {
        int i = (bid - PREP_ZERO_B - 1) * 256 + tid;
        if (i < NNODES * DIN / 4) {
            float4 v = reinterpret_cast<const float4*>(a.x)[i];
            ushort4v o = {f2bf(v.x), f2bf(v.y), f2bf(v.z), f2bf(v.w)};
            reinterpret_cast<ushort4v*>(a.xb)[i] = o;
        }
    } else {
        // transpose+convert one 32x32 tile: src fp32 [K][256] -> dst bf16 [256][K]
        int wb = bid - (PREP_ZERO_B + 1 + PREP_XCONV_B);
        int m, t32;
        if (wb < 32) { m = 0; t32 = wb; }
        else { m = 1 + (wb - 32) / 64; t32 = (wb - 32) % 64; }
        int kb = a.wkbits[m];
        int K = 1 << kb;
        int tc = t32 & 7, tr = t32 >> 3;          // tr < K/32
        int r = tid >> 3, c4 = (tid & 7) * 4;     // load coalesced rows
        float4 v = *reinterpret_cast<const float4*>(
            &a.wsrc[m][(size_t)(tr * 32 + r) * 256 + tc * 32 + c4]);
        tile[r][c4 + 0] = v.x; tile[r][c4 + 1] = v.y;
        tile[r][c4 + 2] = v.z; tile[r][c4 + 3] = v.w;
        __syncthreads();
        int cc = tid >> 3, k4 = (tid & 7) * 4;    // write coalesced dst rows
        ushort4v o = {f2bf(tile[k4 + 0][cc]), f2bf(tile[k4 + 1][cc]),
                      f2bf(tile[k4 + 2][cc]), f2bf(tile[k4 + 3][cc])};
        *reinterpret_cast<ushort4v*>(
            &a.wdst[m][(size_t)(tc * 32 + cc) * K + tr * 32 + k4]) = o;
    }
}

__device__ __forceinline__ int eload(const int* __restrict__ eb, int is32, long logical_idx) {
    return is32 ? eb[logical_idx] : eb[2 * logical_idx]; // little-endian low word
}

__global__ void hist_kernel(const int* __restrict__ eb, const int* __restrict__ flag,
                            int* __restrict__ cnt, int E) {
    int i = blockIdx.x * blockDim.x + threadIdx.x;
    if (i >= E) return;
    int is32 = flag[0];
    int d = eload(eb, is32, (long)E + i);
    atomicAdd(&cnt[d], 1);
}

// single-block exclusive scan over N counts -> offs[N+1], cursor copy.
// Wave-shuffle scan: per-wave __shfl_up inclusive scan, 16 wave sums scanned
// by wave 0, 2 barriers total.
__global__ __launch_bounds__(1024) void scan_kernel(const int* __restrict__ cnt,
                                                    int* __restrict__ offs,
                                                    int* __restrict__ cursor, int n) {
    __shared__ int wsums[16];
    int tid = threadIdx.x, lane = tid & 63, wid = tid >> 6;
    int per = (n + 1023) / 1024;          // 10 for n=10000
    int beg = tid * per;
    int local[16];
    int s = 0;
    for (int i = 0; i < per; ++i) {
        int idx = beg + i;
        int v = (idx < n) ? cnt[idx] : 0;
        local[i] = s;
        s += v;
    }
    int inc = s;                           // inclusive scan within wave
    for (int d = 1; d < 64; d <<= 1) {
        int y = __shfl_up(inc, d, 64);
        if (lane >= d) inc += y;
    }
    if (lane == 63) wsums[wid] = inc;
    __syncthreads();
    if (tid < 16) {
        int v = wsums[tid];
        for (int d = 1; d < 16; d <<= 1) {
            int y = __shfl_up(v, d, 64);
            if (tid >= d) v += y;
        }
        wsums[tid] = v;                    // inclusive wave-sum prefix
    }
    __syncthreads();
    int wbase = (wid > 0) ? wsums[wid - 1] : 0;
    int base = wbase + inc - s;            // exclusive prefix of this chunk
    for (int i = 0; i < per; ++i) {
        int idx = beg + i;
        if (idx < n) {
            int v = base + local[i];
            offs[idx] = v;
            cursor[idx] = v;
        }
    }
    if (tid == 1023) offs[n] = wbase + inc;
}

__global__ void scatter_kernel(const int* __restrict__ eb, const int* __restrict__ flag,
                               int* __restrict__ cursor, int* __restrict__ srcs, int E) {
    int i = blockIdx.x * blockDim.x + threadIdx.x;
    if (i >= E) return;
    int is32 = flag[0];
    int s = eload(eb, is32, (long)i);
    int d = eload(eb, is32, (long)E + i);
    int pos = atomicAdd(&cursor[d], 1);
    srcs[pos] = s;
}

// --- sliced bf16 aggregation: h[i] = z[i] + sum_{e in CSR[i]} z[src_e].
// 128B slices: LPN=8 lanes x ushort8 (16B) = one 128B cache line per
// node-slice. slice = bid & (NSLICE-1) -> round-robin XCD binding; per-XCD
// working set N*128B = 1.28 MB (L2-resident). 4 gather chains + software-
// pipelined srcs prefetch.
template <int D>
__global__ __launch_bounds__(256) void agg_add_sliced_kernel(const unsigned short* __restrict__ z,
                                                             const int* __restrict__ srcs,
                                                             const int* __restrict__ offs,
                                                             unsigned short* __restrict__ h, int n) {
    constexpr int NSLICE = (D * 2) / 128;  // 4 for D=256, 2 for D=128
    constexpr int LPN = 8;                 // 8 lanes x 16B = 128B per node-slice
    constexpr int NPB = 256 / LPN;         // 32 nodes per block
    int bid = blockIdx.x;
    int slice = bid & (NSLICE - 1);
    int ng = bid / NSLICE;
    int t = threadIdx.x;
    int node = ng * NPB + t / LPN;
    if (node >= n) return;
    int li = t % LPN;
    int col8 = slice * LPN + li;          // ushort8 column index within row
    const ushort8v* zb = reinterpret_cast<const ushort8v*>(z);
    const int ld8 = D / 8;
    int beg = offs[node], end = offs[node + 1];

    float a0[8] = {}, a1[8] = {}, a2[8] = {}, a3[8] = {};
    int e = beg;
    if (e + 4 <= end) {
        int s0 = srcs[e], s1 = srcs[e + 1], s2 = srcs[e + 2], s3 = srcs[e + 3];
        while (true) {
            int n0 = 0, n1 = 0, n2 = 0, n3 = 0;
            bool more = (e + 8 <= end);
            if (more) {
                n0 = srcs[e + 4]; n1 = srcs[e + 5];
                n2 = srcs[e + 6]; n3 = srcs[e + 7];
            }
            ushort8v v0 = zb[(size_t)s0 * ld8 + col8];
            ushort8v v1 = zb[(size_t)s1 * ld8 + col8];
            ushort8v v2 = zb[(size_t)s2 * ld8 + col8];
            ushort8v v3 = zb[(size_t)s3 * ld8 + col8];
#pragma unroll
            for (int j = 0; j < 8; ++j) {
                a0[j] += bf2f(v0[j]);
                a1[j] += bf2f(v1[j]);
                a2[j] += bf2f(v2[j]);
                a3[j] += bf2f(v3[j]);
            }
            e += 4;
            if (!more) break;
            s0 = n0; s1 = n1; s2 = n2; s3 = n3;
        }
    }
    for (; e < end; ++e) {
        ushort8v v = zb[(size_t)srcs[e] * ld8 + col8];
#pragma unroll
        for (int j = 0; j < 8; ++j) a0[j] += bf2f(v[j]);
    }
    ushort8v zr = zb[(size_t)node * ld8 + col8];   // residual z term
    ushort8v o;
#pragma unroll
    for (int j = 0; j < 8; ++j) {
        float v = a0[j] + a1[j] + a2[j] + a3[j] + bf2f(zr[j]);
        o[j] = f2bf(v);
    }
    reinterpret_cast<ushort8v*>(h)[(size_t)node * ld8 + col8] = o;
}

// --- fused MLP (r16 best): C = relu( relu(A@W1+b1) @ W2 + b2 ).
// 512 threads / 8 waves; wave grid 2x4 (wr=wave>>2, wc=wave&3), 32x64/wave.
// T14 async-stage: next W slice -> 8 ushort8v regs during current MFMA;
// regs -> LDS after consumed-barrier. Same Bs slots, same k-order.
// MFMA layouts (m89-verified): A-frag row=lane&15, k=(lane>>4)*8+j;
// C/D col=lane&15, row=(lane>>4)*4+j.
template <int K, int OUT_BF16>
__global__ __launch_bounds__(512) void mlp_fused_kernel(const unsigned short* __restrict__ A,
                                                        const unsigned short* __restrict__ Wt1,
                                                        const float* __restrict__ b1,
                                                        const unsigned short* __restrict__ Wt2,
                                                        const float* __restrict__ b2,
                                                        void* __restrict__ C, int M) {
    constexpr int NK = K / 32;                   // k-chunks in A (4 or 8)
    constexpr int NST1 = K / 128;                // phase-1 W stages (1 or 2)
    __shared__ unsigned short As[NK][4][64][8];  // 16/32 KB  full A tile
    __shared__ unsigned short Bs[4][4][256][8];  // 64 KB     128-k x 256-col W slice
    __shared__ unsigned short Ts[8][4][64][8];   // 32 KB     t tile
    int tid = threadIdx.x;
    int wave = tid >> 6, lane = tid & 63;
    int wr = wave >> 2, wc = wave & 3;           // 2x4 wave grid
    int m0 = blockIdx.x * 64;
    int fr = lane & 15;        // fragment row/col
    int kc = lane >> 4;        // fragment k-chunk (== rg for C/D rows)
    int scol = tid >> 2;       // staging col 0..127
    int sscn = tid & 3;        // staging k-subchunk 0..3

    f32x4 acc[2][4];
#pragma unroll
    for (int i = 0; i < 2; ++i)
#pragma unroll
        for (int j = 0; j < 4; ++j) acc[i][j] = (f32x4){0.f, 0.f, 0.f, 0.f};

    ushort8v wreg[8];
#define LOAD_W(Wp, ldk, st)                                                   \
    {                                                                         \
        _Pragma("unroll")                                                     \
        for (int cp = 0; cp < 2; ++cp) {                                      \
            _Pragma("unroll")                                                 \
            for (int kk = 0; kk < 4; ++kk)                                    \
                wreg[cp * 4 + kk] = *reinterpret_cast<const ushort8v*>(       \
                    &(Wp)[(size_t)(cp * 128 + scol) * (ldk) + (st) * 128 +    \
                          kk * 32 + sscn * 8]);                               \
        }                                                                     \
    }
#define WRITE_W()                                                             \
    {                                                                         \
        _Pragma("unroll")                                                     \
        for (int cp = 0; cp < 2; ++cp) {                                      \
            _Pragma("unroll")                                                 \
            for (int kk = 0; kk < 4; ++kk)                                    \
                *reinterpret_cast<ushort8v*>(                                 \
                    &Bs[kk][sscn][cp * 128 + scol][0]) = wreg[cp * 4 + kk];   \
        }                                                                     \
    }

    auto compute_p1 = [&](int st) {
#pragma unroll
        for (int kk = 0; kk < 4; ++kk) {
            bf16x8 af[2];
#pragma unroll
            for (int i = 0; i < 2; ++i)
                af[i] = __builtin_bit_cast(bf16x8,
                    *reinterpret_cast<const ushort8v*>(&As[st * 4 + kk][kc][wr * 32 + i * 16 + fr][0]));
#pragma unroll
            for (int j = 0; j < 4; ++j) {
                bf16x8 bf = __builtin_bit_cast(bf16x8,
                    *reinterpret_cast<const ushort8v*>(&Bs[kk][kc][wc * 64 + j * 16 + fr][0]));
#pragma unroll
                for (int i = 0; i < 2; ++i)
                    acc[i][j] = __builtin_amdgcn_mfma_f32_16x16x32_bf16(af[i], bf, acc[i][j], 0, 0, 0);
            }
        }
    };
    auto compute_p2 = [&](int st) {
#pragma unroll
        for (int kk = 0; kk < 4; ++kk) {
            bf16x8 af[2];
#pragma unroll
            for (int i = 0; i < 2; ++i)
                af[i] = __builtin_bit_cast(bf16x8,
                    *reinterpret_cast<const ushort8v*>(&Ts[st * 4 + kk][kc][wr * 32 + i * 16 + fr][0]));
#pragma unroll
            for (int j = 0; j < 4; ++j) {
                bf16x8 bf = __builtin_bit_cast(bf16x8,
                    *reinterpret_cast<const ushort8v*>(&Bs[kk][kc][wc * 64 + j * 16 + fr][0]));
#pragma unroll
                for (int i = 0; i < 2; ++i)
                    acc[i][j] = __builtin_amdgcn_mfma_f32_16x16x32_bf16(af[i], bf, acc[i][j], 0, 0, 0);
            }
        }
    };
    auto epilogue1 = [&]() {
#pragma unroll
        for (int i = 0; i < 2; ++i)
#pragma unroll
            for (int j = 0; j < 4; ++j) {
                int col = wc * 64 + j * 16 + fr;
                float bb = b1[col];
#pragma unroll
                for (int jj = 0; jj < 4; ++jj) {
                    int row = wr * 32 + i * 16 + kc * 4 + jj;
                    float v = fmaxf(acc[i][j][jj] + bb, 0.f);
                    Ts[col >> 5][(col >> 3) & 3][row][col & 7] = f2bf(v);
                }
                acc[i][j] = (f32x4){0.f, 0.f, 0.f, 0.f};
            }
    };

    // ---- W1 st0 -> regs; stage full A tile; regs -> LDS
    LOAD_W(Wt1, K, 0);
    {
        int row = tid >> 3, c0 = tid & 7;
        int gr = m0 + row;
#pragma unroll
        for (int i = 0; i < K / 64; ++i) {
            int chunk = c0 + i * 8;
            ushort8v av = {0, 0, 0, 0, 0, 0, 0, 0};
            if (gr < M) av = *reinterpret_cast<const ushort8v*>(&A[(size_t)gr * K + chunk * 8]);
            *reinterpret_cast<ushort8v*>(&As[chunk >> 2][chunk & 3][row][0]) = av;
        }
    }
    WRITE_W();
    // prefetch next slice while st0 is consumed
    if (NST1 > 1) { LOAD_W(Wt1, K, 1); } else { LOAD_W(Wt2, 256, 0); }
    __syncthreads();               // As + Bs(st0) ready
    compute_p1(0);
    if (NST1 == 1) epilogue1();
    __syncthreads();               // Bs consumed (+Ts ready if NST1==1)
    WRITE_W();
    if (NST1 > 1) { LOAD_W(Wt2, 256, 0); } else { LOAD_W(Wt2, 256, 1); }
    __syncthreads();               // Bs ready
    if (NST1 > 1) {
        compute_p1(1);
        epilogue1();
        __syncthreads();           // Bs consumed + Ts ready
        WRITE_W();                 // W2 st0
        LOAD_W(Wt2, 256, 1);
        __syncthreads();           // Bs ready
    }
    compute_p2(0);
    __syncthreads();               // Bs consumed
    WRITE_W();                     // W2 st1
    __syncthreads();               // Bs ready
    compute_p2(1);

    // ---- epilogue 2 -> global
#pragma unroll
    for (int i = 0; i < 2; ++i)
#pragma unroll
        for (int j = 0; j < 4; ++j) {
            int col = wc * 64 + j * 16 + fr;
            float bb = b2[col];
#pragma unroll
            for (int jj = 0; jj < 4; ++jj) {
                int row = m0 + wr * 32 + i * 16 + kc * 4 + jj;
                if (row < M) {
                    float v = fmaxf(acc[i][j][jj] + bb, 0.f);
                    if (OUT_BF16)
                        ((unsigned short*)C)[(size_t)row * 256 + col] = f2bf(v);
                    else
                        ((float*)C)[(size_t)row * 256 + col] = v;
                }
            }
        }
#undef LOAD_W
#undef WRITE_W
}

extern "C" void kernel_launch(void* const* d_in, const int* in_sizes, int n_in,
                              void* d_out, int out_size, void* d_ws, size_t ws_size,
                              hipStream_t stream) {
    const float* x = (const float*)d_in[0];
    const int* eb = (const int*)d_in[1];
    const int E = NEDGES;
    const int N = NNODES;

    const float* w1[3] = {(const float*)d_in[2], (const float*)d_in[6], (const float*)d_in[10]};
    const float* b1[3] = {(const float*)d_in[3], (const float*)d_in[7], (const float*)d_in[11]};
    const float* w2[3] = {(const float*)d_in[4], (const float*)d_in[8], (const float*)d_in[12]};
    const float* b2[3] = {(const float*)d_in[5], (const float*)d_in[9], (const float*)d_in[13]};

    // workspace layout
    char* ws = (char*)d_ws;
    size_t off = 0;
    auto alloc = [&](size_t bytes) {
        void* p = ws + off;
        off += (bytes + 255) & ~(size_t)255;
        return p;
    };
    int* flag   = (int*)alloc(4);
    int* cnt    = (int*)alloc((size_t)N * 4);
    int* offs   = (int*)alloc((size_t)(N + 1) * 4);
    int* cursor = (int*)alloc((size_t)N * 4);
    int* srcs   = (int*)alloc((size_t)E * 4);
    unsigned short* xb   = (unsigned short*)alloc((size_t)N * DIN * 2);
    unsigned short* zbuf = (unsigned short*)alloc((size_t)N * DH * 2);
    unsigned short* hbuf = (unsigned short*)alloc((size_t)N * DH * 2);
    unsigned short* wt[6];
    wt[0] = (unsigned short*)alloc((size_t)DIN * DH * 2);          // w1_0^T: 256x128
    for (int i = 1; i < 6; ++i) wt[i] = (unsigned short*)alloc((size_t)DH * DH * 2);
    (void)ws_size; (void)n_in; (void)out_size; (void)in_sizes;

    // --- fused prep (zero cnt | detect | x->bf16 | weights ->bf16 transposed)
    PrepArgs pa;
    pa.wsrc[0] = w1[0]; pa.wsrc[1] = w2[0]; pa.wsrc[2] = w1[1];
    pa.wsrc[3] = w2[1]; pa.wsrc[4] = w1[2]; pa.wsrc[5] = w2[2];
    for (int i = 0; i < 6; ++i) pa.wdst[i] = wt[i];
    pa.wkbits[0] = 7;
    for (int i = 1; i < 6; ++i) pa.wkbits[i] = 8;
    pa.eb = eb; pa.flag = flag; pa.cnt = cnt; pa.x = x; pa.xb = xb;
    prep_kernel<<<PREP_GRID, 256, 0, stream>>>(pa);

    // --- CSR build
    hist_kernel<<<(E + 255) / 256, 256, 0, stream>>>(eb, flag, cnt, E);
    scan_kernel<<<1, 1024, 0, stream>>>(cnt, offs, cursor, N);
    scatter_kernel<<<(E + 255) / 256, 256, 0, stream>>>(eb, flag, cursor, srcs, E);

    int mlp_grid = (N + 63) / 64;               // 157 blocks
    int agg_blocks_256 = ((N + 31) / 32) * 4;   // D=256: 32 nodes/block, 4 slices
    int agg_blocks_128 = ((N + 31) / 32) * 2;   // D=128: 32 nodes/block, 2 slices

    // --- layer 0 (K = 128)
    agg_add_sliced_kernel<128><<<agg_blocks_128, 256, 0, stream>>>(xb, srcs, offs, hbuf, N);
    mlp_fused_kernel<128, 1><<<mlp_grid, 512, 0, stream>>>(hbuf, wt[0], b1[0], wt[1], b2[0], zbuf, N);

    // --- layer 1
    agg_add_sliced_kernel<256><<<agg_blocks_256, 256, 0, stream>>>(zbuf, srcs, offs, hbuf, N);
    mlp_fused_kernel<256, 1><<<mlp_grid, 512, 0, stream>>>(hbuf, wt[2], b1[1], wt[3], b2[1], zbuf, N);

    // --- layer 2 (final output fp32 to d_out)
    agg_add_sliced_kernel<256><<<agg_blocks_256, 256, 0, stream>>>(zbuf, srcs, offs, hbuf, N);
    mlp_fused_kernel<256, 0><<<mlp_grid, 512, 0, stream>>>(hbuf, wt[4], b1[2], wt[5], b2[2], (float*)d_out, N);
}